// Round 4
// baseline (2895.341 us; speedup 1.0000x reference)
//
#include <hip/hip_runtime.h>
#include <stdint.h>

// ---------------------------------------------------------------------------
// Discriminator_RNN_Utt: 2-layer GRU (B=1024,T=63,F=257,H=512) + MLP heads.
// v3: swapped MFMA roles (A=weights/units, B=batch), XCD-aligned weight
// slices (m = bid%8 -> L2-resident), bf16 x, vectorized epilogues, NT streams.
// Pipeline: phase p runs XG(t=p) | L0(t=p-1) | L1(t=p-2), 65 phases.
// ---------------------------------------------------------------------------

typedef __bf16 bf16x8 __attribute__((ext_vector_type(8)));
typedef float f32x4 __attribute__((ext_vector_type(4)));
typedef unsigned int u32x2 __attribute__((ext_vector_type(2)));
typedef unsigned int u32x4 __attribute__((ext_vector_type(4)));

__device__ __forceinline__ unsigned short f2bf(float f) {
  unsigned int u = __float_as_uint(f);
  u += 0x7fffu + ((u >> 16) & 1u);   // RNE
  return (unsigned short)(u >> 16);
}
__device__ __forceinline__ float bf2f(unsigned short s) {
  return __uint_as_float(((unsigned int)s) << 16);
}
__device__ __forceinline__ float sigm(float x) { return 1.f / (1.f + __expf(-x)); }
__device__ __forceinline__ float tanh_(float x) { return 1.f - 2.f / (1.f + __expf(2.f * x)); }

__device__ __forceinline__ bf16x8 ld_frag(const unsigned short* p) {
  uint4 u = *(const uint4*)p;
  return __builtin_bit_cast(bf16x8, u);
}
// 8B = 4 bf16 -> 4 floats (non-temporal)
__device__ __forceinline__ void ld_bf4_nt(const unsigned short* p, float* f) {
  u32x2 v = __builtin_nontemporal_load((const u32x2*)p);
  f[0] = bf2f((unsigned short)(v[0] & 0xffff));
  f[1] = bf2f((unsigned short)(v[0] >> 16));
  f[2] = bf2f((unsigned short)(v[1] & 0xffff));
  f[3] = bf2f((unsigned short)(v[1] >> 16));
}
__device__ __forceinline__ void st_bf4_nt(unsigned short* p, const float* f) {
  u32x2 v;
  v[0] = (unsigned)f2bf(f[0]) | ((unsigned)f2bf(f[1]) << 16);
  v[1] = (unsigned)f2bf(f[2]) | ((unsigned)f2bf(f[3]) << 16);
  __builtin_nontemporal_store(v, (u32x2*)p);
}

// ------------------------- fp32 -> bf16 (+row pad) -------------------------
__global__ void conv_pad_kernel(const float* __restrict__ src,
                                unsigned short* __restrict__ dst,
                                int rows, int sk, int dk) {
  int idx = blockIdx.x * 256 + threadIdx.x;  // one per 8 outputs
  int cpr = dk >> 3;
  if (idx >= rows * cpr) return;
  int row = idx / cpr;
  int c0 = (idx - row * cpr) << 3;
  const float* s = src + (size_t)row * sk;
  union { unsigned short v[8]; uint4 u; } t;
#pragma unroll
  for (int j = 0; j < 8; ++j) {
    int c = c0 + j;
    t.v[j] = (c < sk) ? f2bf(s[c]) : (unsigned short)0;
  }
  *(uint4*)(dst + (size_t)row * dk + c0) = t.u;
}

// ---------------- zero a contiguous region (g0, q0, x3) --------------------
__global__ void zero_ws_kernel(uint4* __restrict__ a, int n) {
  int i = blockIdx.x * 256 + threadIdx.x;
  uint4 z = {0u, 0u, 0u, 0u};
  if (i < n) a[i] = z;
}

// --------------------- fused GRU phase (pipelined) -------------------------
// blocks 0..127  : layer0 t=p-1 (1<=p<=63)  Btile=64,  m=bid%8 (64 units)
// blocks 128..383: layer1 t=p-2 (p>=2)      Btile=32,  m=bid%8, + x3 accum
// blocks 384..447: xg(t=p)      (p<=62)     Btile=128, u=bid%8 (192 units)
__global__ __launch_bounds__(512) void gru_phase_kernel(
    const unsigned short* __restrict__ xb,     // [1024*63][288] bf16
    const unsigned short* __restrict__ wih0b, const float* __restrict__ bih0,
    unsigned short* __restrict__ xgcur,        // xgbuf[p&1]     (XG out)
    const unsigned short* __restrict__ xgprev, // xgbuf[(p+1)&1] (L0 in)
    const unsigned short* __restrict__ gA,     // gbuf[(p+1)&1]  (L0 h_prev, L1 g)
    unsigned short* __restrict__ gB,           // gbuf[p&1]      (L0 h_new)
    const unsigned short* __restrict__ qA,     // qbuf[p&1]      (L1 h_prev)
    unsigned short* __restrict__ qB,           // qbuf[(p+1)&1]  (L1 h_new)
    const unsigned short* __restrict__ whh0, const float* __restrict__ bhh0,
    const unsigned short* __restrict__ wih1, const unsigned short* __restrict__ whh1,
    const float* __restrict__ bih1, const float* __restrict__ bhh1,
    const float* __restrict__ dnnw, float* __restrict__ x3, int p) {
  __shared__ __align__(16) unsigned short sm[32768];  // 64KB
  const int tid = threadIdx.x;
  const int lane = tid & 63, w = tid >> 6;
  const int lm = lane & 15, lk = lane >> 4;
  const int mg = w & 3, ng = w >> 2;   // 4 unit-groups x 2 batch-groups
  const int bid = blockIdx.x;

  if (bid < 128) {  // ---------------- layer 0, t = p-1 ----------------
    if (p < 1 || p > 63) return;
    const int m0 = (bid & 7) * 64;      // unit slice (XCD-aligned)
    const int b0 = (bid >> 3) * 64;     // 16 b-tiles of 64
    // stage h1_prev[b0..b0+63][0..511] -> LDS, XOR-swizzled, NT
#pragma unroll
    for (int s = 0; s < 8; ++s) {
      int c = tid + (s << 9);
      int row = c >> 6, ch = c & 63, sw = ch ^ (row & 7);
      *(u32x4*)&sm[row * 512 + sw * 8] = __builtin_nontemporal_load(
          (const u32x4*)(gA + ((size_t)(b0 + row) << 9) + ch * 8));
    }
    __syncthreads();
    f32x4 acc[3][2];
#pragma unroll
    for (int g = 0; g < 3; ++g)
#pragma unroll
      for (int nb = 0; nb < 2; ++nb) acc[g][nb] = {0.f, 0.f, 0.f, 0.f};
    const int urow = m0 + mg * 16 + lm;   // A-frag weight row (per gate)
    for (int kk = 0; kk < 16; ++kk) {
      bf16x8 ag[3];
#pragma unroll
      for (int g = 0; g < 3; ++g)
        ag[g] = ld_frag(whh0 + ((size_t)(g * 512 + urow) << 9) + kk * 32 + lk * 8);
#pragma unroll
      for (int nb = 0; nb < 2; ++nb) {
        int row = ng * 32 + nb * 16 + lm;
        int sw = (kk * 4 + lk) ^ (row & 7);
        bf16x8 hb = ld_frag(&sm[row * 512 + sw * 8]);
#pragma unroll
        for (int g = 0; g < 3; ++g)
          acc[g][nb] = __builtin_amdgcn_mfma_f32_16x16x32_bf16(ag[g], hb, acc[g][nb], 0, 0, 0);
      }
    }
    const int ug = m0 + mg * 16 + lk * 4;      // 4 consecutive units per lane
    const f32x4 br4 = *(const f32x4*)(bhh0 + ug);
    const f32x4 bz4 = *(const f32x4*)(bhh0 + 512 + ug);
    const f32x4 bn4 = *(const f32x4*)(bhh0 + 1024 + ug);
#pragma unroll
    for (int nb = 0; nb < 2; ++nb) {
      int rowl = ng * 32 + nb * 16 + lm;
      int brow = b0 + rowl;
      const unsigned short* xr = xgprev + (size_t)brow * 1536;
      float ir[4], iz[4], in_[4], hp[4], hv[4];
      ld_bf4_nt(xr + ug, ir);
      ld_bf4_nt(xr + 512 + ug, iz);
      ld_bf4_nt(xr + 1024 + ug, in_);
      int cu = ug >> 3, swc = cu ^ (rowl & 7);
      const unsigned short* hpp = &sm[rowl * 512 + swc * 8 + (ug & 7)];
#pragma unroll
      for (int r = 0; r < 4; ++r) hp[r] = bf2f(hpp[r]);
#pragma unroll
      for (int r = 0; r < 4; ++r) {
        float rr = sigm(ir[r] + acc[0][nb][r] + br4[r]);
        float zz = sigm(iz[r] + acc[1][nb][r] + bz4[r]);
        float nn = tanh_(in_[r] + rr * (acc[2][nb][r] + bn4[r]));
        hv[r] = nn - nn * zz + zz * hp[r];
      }
      st_bf4_nt(gB + ((size_t)brow << 9) + ug, hv);
    }
  } else if (bid < 384) {  // ---------------- layer 1, t = p-2 ----------------
    if (p < 2) return;
    const int lb = bid - 128;
    const int m0 = (lb & 7) * 64;
    const int b0 = (lb >> 3) * 32;      // 32 b-tiles of 32
    const int t = p - 2;
    unsigned short* smA = sm;           // g (h1 cur)  [32][512]
    unsigned short* smB = sm + 16384;   // q (h2 prev) [32][512]
#pragma unroll
    for (int s = 0; s < 4; ++s) {
      int c = tid + (s << 9);
      int row = c >> 6, ch = c & 63, sw = ch ^ (row & 7);
      size_t go = ((size_t)(b0 + row) << 9) + ch * 8;
      *(u32x4*)&smA[row * 512 + sw * 8] = __builtin_nontemporal_load((const u32x4*)(gA + go));
      *(u32x4*)&smB[row * 512 + sw * 8] = __builtin_nontemporal_load((const u32x4*)(qA + go));
    }
    __syncthreads();
    f32x4 aI[3], aH[3];
#pragma unroll
    for (int g = 0; g < 3; ++g) { aI[g] = {0.f, 0.f, 0.f, 0.f}; aH[g] = {0.f, 0.f, 0.f, 0.f}; }
    const int urow = m0 + mg * 16 + lm;
    const int rowl = ng * 16 + lm;      // wave's single n-frag
    for (int kk = 0; kk < 16; ++kk) {
      bf16x8 wi[3], wh[3];
#pragma unroll
      for (int g = 0; g < 3; ++g) {
        size_t wro = ((size_t)(g * 512 + urow) << 9) + kk * 32 + lk * 8;
        wi[g] = ld_frag(wih1 + wro);
        wh[g] = ld_frag(whh1 + wro);
      }
      int sw = (kk * 4 + lk) ^ (rowl & 7);
      bf16x8 gb = ld_frag(&smA[rowl * 512 + sw * 8]);
      bf16x8 qb = ld_frag(&smB[rowl * 512 + sw * 8]);
#pragma unroll
      for (int g = 0; g < 3; ++g) {
        aI[g] = __builtin_amdgcn_mfma_f32_16x16x32_bf16(wi[g], gb, aI[g], 0, 0, 0);
        aH[g] = __builtin_amdgcn_mfma_f32_16x16x32_bf16(wh[g], qb, aH[g], 0, 0, 0);
      }
    }
    const int ug = m0 + mg * 16 + lk * 4;
    const f32x4 bir4 = *(const f32x4*)(bih1 + ug);
    const f32x4 biz4 = *(const f32x4*)(bih1 + 512 + ug);
    const f32x4 bin4 = *(const f32x4*)(bih1 + 1024 + ug);
    const f32x4 bhr4 = *(const f32x4*)(bhh1 + ug);
    const f32x4 bhz4 = *(const f32x4*)(bhh1 + 512 + ug);
    const f32x4 bhn4 = *(const f32x4*)(bhh1 + 1024 + ug);
    const f32x4 dw4  = *(const f32x4*)(dnnw + ug);
    const int brow = b0 + rowl;
    float hp[4], hv[4];
    int cu = ug >> 3, swc = cu ^ (rowl & 7);
    const unsigned short* hpp = &smB[rowl * 512 + swc * 8 + (ug & 7)];
#pragma unroll
    for (int r = 0; r < 4; ++r) hp[r] = bf2f(hpp[r]);
    float v = 0.f;
#pragma unroll
    for (int r = 0; r < 4; ++r) {
      float rr = sigm(aI[0][r] + aH[0][r] + bir4[r] + bhr4[r]);
      float zz = sigm(aI[1][r] + aH[1][r] + biz4[r] + bhz4[r]);
      float nn = tanh_(aI[2][r] + bin4[r] + rr * (aH[2][r] + bhn4[r]));
      hv[r] = nn - nn * zz + zz * hp[r];
      v += hv[r] * dw4[r];
    }
    st_bf4_nt(qB + ((size_t)brow << 9) + ug, hv);
    // dnn head partial: sum 16 units of this mg across lk, then across waves
    v += __shfl_xor(v, 16);
    v += __shfl_xor(v, 32);
    __syncthreads();                    // tiles dead; reuse LDS for partials
    float* part = (float*)sm;
    if (tid < 32) part[tid] = 0.f;
    __syncthreads();
    if (lk == 0) atomicAdd(&part[rowl], v);
    __syncthreads();
    if (tid < 32) atomicAdd(&x3[(size_t)(b0 + tid) * 63 + t], part[tid]);
  } else {  // ---------------- XG: xg(t=p) = x_t @ w_ih0^T + b_ih0 ----------------
    if (p > 62) return;
    const int t = p;
    const int lg = bid - 384;
    const int U0 = (lg & 7) * 192;      // 8 unit-slices of 192 (XCD-aligned)
    const int b0 = (lg >> 3) * 128;     // 8 b-tiles of 128
    f32x4 acc[3][4];
#pragma unroll
    for (int f = 0; f < 3; ++f)
#pragma unroll
      for (int nb = 0; nb < 4; ++nb) acc[f][nb] = {0.f, 0.f, 0.f, 0.f};
    const int ub = U0 + mg * 48;
    for (int kk = 0; kk < 9; ++kk) {
      bf16x8 af[3];
#pragma unroll
      for (int f = 0; f < 3; ++f)
        af[f] = ld_frag(wih0b + (size_t)(ub + f * 16 + lm) * 288 + kk * 32 + lk * 8);
#pragma unroll
      for (int nb = 0; nb < 4; ++nb) {
        int brow = b0 + ng * 64 + nb * 16 + lm;
        bf16x8 xv = ld_frag(xb + ((size_t)brow * 63 + t) * 288 + kk * 32 + lk * 8);
#pragma unroll
        for (int f = 0; f < 3; ++f)
          acc[f][nb] = __builtin_amdgcn_mfma_f32_16x16x32_bf16(af[f], xv, acc[f][nb], 0, 0, 0);
      }
    }
#pragma unroll
    for (int f = 0; f < 3; ++f) {
      int ug = ub + f * 16 + lk * 4;
      const f32x4 bv4 = *(const f32x4*)(bih0 + ug);
#pragma unroll
      for (int nb = 0; nb < 4; ++nb) {
        int brow = b0 + ng * 64 + nb * 16 + lm;
        float o[4];
#pragma unroll
        for (int r = 0; r < 4; ++r) o[r] = acc[f][nb][r] + bv4[r];
        st_bf4_nt(xgcur + (size_t)brow * 1536 + ug, o);
      }
    }
  }
}

// ------------------------------- heads -------------------------------------
__global__ __launch_bounds__(64) void head_kernel(
    const float* __restrict__ x3, const float* __restrict__ dnn_b,
    const float* __restrict__ w1, const float* __restrict__ b1,
    const float* __restrict__ w2, const float* __restrict__ b2,
    const float* __restrict__ w3, const float* __restrict__ b3,
    float* __restrict__ out) {
  __shared__ float x3s[63], x4[32], x5[16];
  const int b = blockIdx.x, l = threadIdx.x;
  if (l < 63) x3s[l] = x3[(size_t)b * 63 + l] + dnn_b[0];
  __syncthreads();
  if (l < 32) {
    float s = b1[l];
    for (int t = 0; t < 63; ++t) s += x3s[t] * w1[l * 63 + t];
    x4[l] = s;
  }
  __syncthreads();
  if (l < 16) {
    float s = b2[l];
#pragma unroll
    for (int j = 0; j < 32; ++j) s += x4[j] * w2[l * 32 + j];
    x5[l] = s;
  }
  __syncthreads();
  if (l == 0) {
    float s = b3[0];
#pragma unroll
    for (int j = 0; j < 16; ++j) s += x5[j] * w3[j];
    out[b] = s;
  }
}

// ---------------------------------------------------------------------------
extern "C" void kernel_launch(void* const* d_in, const int* in_sizes, int n_in,
                              void* d_out, int out_size, void* d_ws, size_t ws_size,
                              hipStream_t stream) {
  const float* x    = (const float*)d_in[0];
  const float* wih0 = (const float*)d_in[1];
  const float* whh0 = (const float*)d_in[2];
  const float* bih0 = (const float*)d_in[3];
  const float* bhh0 = (const float*)d_in[4];
  const float* wih1 = (const float*)d_in[5];
  const float* whh1 = (const float*)d_in[6];
  const float* bih1 = (const float*)d_in[7];
  const float* bhh1 = (const float*)d_in[8];
  const float* dnnw = (const float*)d_in[9];
  const float* dnnb = (const float*)d_in[10];
  const float* w1   = (const float*)d_in[11];
  const float* b1   = (const float*)d_in[12];
  const float* w2   = (const float*)d_in[13];
  const float* b2   = (const float*)d_in[14];
  const float* w3   = (const float*)d_in[15];
  const float* b3   = (const float*)d_in[16];
  float* out = (float*)d_out;

  char* p = (char*)d_ws;
  auto alloc = [&](size_t bytes) {
    char* r = p;
    p += (bytes + 255) & ~(size_t)255;
    return r;
  };
  // total ~51 MB
  unsigned short* xbuf  = (unsigned short*)alloc((size_t)64512 * 288 * 2);  // x bf16
  unsigned short* xgbuf[2];
  xgbuf[0] = (unsigned short*)alloc((size_t)1024 * 1536 * 2);
  xgbuf[1] = (unsigned short*)alloc((size_t)1024 * 1536 * 2);
  unsigned short* wih0b = (unsigned short*)alloc((size_t)1536 * 288 * 2);
  unsigned short* whh0b = (unsigned short*)alloc((size_t)1536 * 512 * 2);
  unsigned short* wih1b = (unsigned short*)alloc((size_t)1536 * 512 * 2);
  unsigned short* whh1b = (unsigned short*)alloc((size_t)1536 * 512 * 2);
  unsigned short* gbuf[2], *qbuf[2];
  gbuf[0] = (unsigned short*)alloc((size_t)1024 * 512 * 2);   // contiguous with
  qbuf[0] = (unsigned short*)alloc((size_t)1024 * 512 * 2);   // qbuf[0], x3:
  float* x3 = (float*)alloc((size_t)1024 * 63 * 4);           // one zero pass
  gbuf[1] = (unsigned short*)alloc((size_t)1024 * 512 * 2);
  qbuf[1] = (unsigned short*)alloc((size_t)1024 * 512 * 2);
  (void)ws_size; (void)in_sizes; (void)n_in; (void)out_size;

  // zero g0 | q0 | x3 (contiguous, 2355200 B = 147200 uint4)
  zero_ws_kernel<<<576, 256, 0, stream>>>((uint4*)gbuf[0], 147200);

  // x and weights -> bf16 (K 257 padded to 288)
  conv_pad_kernel<<<9072, 256, 0, stream>>>(x, xbuf, 64512, 257, 288);
  conv_pad_kernel<<<216, 256, 0, stream>>>(wih0, wih0b, 1536, 257, 288);
  conv_pad_kernel<<<384, 256, 0, stream>>>(whh0, whh0b, 1536, 512, 512);
  conv_pad_kernel<<<384, 256, 0, stream>>>(wih1, wih1b, 1536, 512, 512);
  conv_pad_kernel<<<384, 256, 0, stream>>>(whh1, whh1b, 1536, 512, 512);

  // pipelined recurrence: phase p = XG(t=p) | L0(t=p-1) | L1(t=p-2)
  for (int ph = 0; ph <= 64; ++ph) {
    gru_phase_kernel<<<448, 512, 0, stream>>>(
        xbuf, wih0b, bih0,
        xgbuf[ph & 1], xgbuf[(ph + 1) & 1],
        gbuf[(ph + 1) & 1], gbuf[ph & 1],
        qbuf[ph & 1], qbuf[(ph + 1) & 1],
        whh0b, bhh0, wih1b, whh1b, bih1, bhh1,
        dnnw, x3, ph);
  }

  // heads -> out [1024]
  head_kernel<<<1024, 64, 0, stream>>>(x3, dnnb, w1, b1, w2, b2, w3, b3, out);
}